// Round 1
// baseline (2329.559 us; speedup 1.0000x reference)
//
#include <hip/hip_runtime.h>
#include <hip/hip_bf16.h>
#include <cstdint>
#include <cstddef>

#define BM 128
#define BN 128
#define BK 32
#define LDS_STRIDE 40  // shorts; 80 B row stride = 5*16B (keeps 16B align, spreads banks)

typedef __attribute__((ext_vector_type(8))) short short8v;
typedef __attribute__((ext_vector_type(4))) short short4v;
typedef __attribute__((ext_vector_type(4))) float f32x4;

__device__ __forceinline__ short f2bf(float f) {
    union { float f; unsigned u; } c; c.f = f;
    unsigned r = c.u + 0x7FFFu + ((c.u >> 16) & 1u);
    return (short)(r >> 16);
}

// C[row, col] = sum_k A[row,k] * W[col,k] + bias[col]
// A: [M x K] row-major, W: [V x K] row-major (i.e. B^T layout), C: [M x V] fp32
__global__ __launch_bounds__(256)
void gemm_bt_kernel(const float* __restrict__ A, const float* __restrict__ W,
                    const float* __restrict__ bias, float* __restrict__ C,
                    int K, int V)
{
    __shared__ short As[BM][LDS_STRIDE];
    __shared__ short Bs[BN][LDS_STRIDE];

    const int tid  = threadIdx.x;
    const int lane = tid & 63;
    const int wave = tid >> 6;
    const int wr = wave >> 1;   // wave row (0..1), owns 64 rows
    const int wc = wave & 1;    // wave col (0..1), owns 64 cols

    const int row0 = blockIdx.y * BM;
    const int col0 = blockIdx.x * BN;

    f32x4 acc[4][4];
#pragma unroll
    for (int m = 0; m < 4; ++m)
#pragma unroll
        for (int n = 0; n < 4; ++n)
            acc[m][n] = (f32x4)(0.0f);

    const int lrow = lane & 15;
    const int kblk = (lane >> 4) * 8;

    for (int k0 = 0; k0 < K; k0 += BK) {
        __syncthreads();
        // stage 128x32 fp32 of A and W -> bf16 LDS (each thread: 4 float4 per matrix)
#pragma unroll
        for (int i = 0; i < 4; ++i) {
            int idx = tid + i * 256;       // 0..1023
            int r   = idx >> 3;            // 0..127
            int c4  = (idx & 7) * 4;       // 0,4,..,28
            float4 va = *reinterpret_cast<const float4*>(&A[(size_t)(row0 + r) * K + k0 + c4]);
            short4v ha = { f2bf(va.x), f2bf(va.y), f2bf(va.z), f2bf(va.w) };
            *reinterpret_cast<short4v*>(&As[r][c4]) = ha;
            float4 vb = *reinterpret_cast<const float4*>(&W[(size_t)(col0 + r) * K + k0 + c4]);
            short4v hb = { f2bf(vb.x), f2bf(vb.y), f2bf(vb.z), f2bf(vb.w) };
            *reinterpret_cast<short4v*>(&Bs[r][c4]) = hb;
        }
        __syncthreads();

        short8v af[4], bfr[4];
#pragma unroll
        for (int m = 0; m < 4; ++m)
            af[m] = *reinterpret_cast<const short8v*>(&As[wr * 64 + m * 16 + lrow][kblk]);
#pragma unroll
        for (int n = 0; n < 4; ++n)
            bfr[n] = *reinterpret_cast<const short8v*>(&Bs[wc * 64 + n * 16 + lrow][kblk]);
#pragma unroll
        for (int m = 0; m < 4; ++m)
#pragma unroll
            for (int n = 0; n < 4; ++n)
                acc[m][n] = __builtin_amdgcn_mfma_f32_16x16x32_bf16(af[m], bfr[n], acc[m][n], 0, 0, 0);
    }

    // epilogue: C/D layout col = lane&15, row = (lane>>4)*4 + j   [m89 verified]
    const int crow_base = row0 + wr * 64 + (lane >> 4) * 4;
    const int ccol_base = col0 + wc * 64 + lrow;
#pragma unroll
    for (int m = 0; m < 4; ++m) {
#pragma unroll
        for (int n = 0; n < 4; ++n) {
            int gc = ccol_base + n * 16;
            float b = bias[gc];
#pragma unroll
            for (int j = 0; j < 4; ++j) {
                int gr = crow_base + m * 16 + j;
                C[(size_t)gr * V + gc] = acc[m][n][j] + b;
            }
        }
    }
}

// Per-row online stats: m = max(x), l1 = sum exp(x-m), lh = sum exp((x-m)/2).
// Writes lse1[r] = m + log l1 (if lse1 != null), lseh[r] = m/2 + log lh.
__global__ __launch_bounds__(256)
void rowstats_kernel(const float* __restrict__ L, int V,
                     float* __restrict__ lse1, float* __restrict__ lseh)
{
    const int r = blockIdx.x;
    const float* x = L + (size_t)r * V;
    const int tid = threadIdx.x;

    float m = -1e30f, l1 = 0.f, lh = 0.f;
    for (int v = tid * 4; v < V; v += 1024) {
        float4 xv = *reinterpret_cast<const float4*>(&x[v]);
        const float* xp = (const float*)&xv;
#pragma unroll
        for (int j = 0; j < 4; ++j) {
            float val = xp[j];
            if (val > m) {
                float d = m - val;
                l1 *= __expf(d);
                lh *= __expf(0.5f * d);
                m = val;
            }
            l1 += __expf(val - m);
            lh += __expf(0.5f * (val - m));
        }
    }
    // wave butterfly combine
#pragma unroll
    for (int off = 32; off > 0; off >>= 1) {
        float mo  = __shfl_xor(m, off);
        float l1o = __shfl_xor(l1, off);
        float lho = __shfl_xor(lh, off);
        float mn = fmaxf(m, mo);
        l1 = l1 * __expf(m - mn) + l1o * __expf(mo - mn);
        lh = lh * __expf(0.5f * (m - mn)) + lho * __expf(0.5f * (mo - mn));
        m = mn;
    }
    __shared__ float sm[4], sl1[4], slh[4];
    if ((tid & 63) == 0) { int w = tid >> 6; sm[w] = m; sl1[w] = l1; slh[w] = lh; }
    __syncthreads();
    if (tid == 0) {
        float M = sm[0], L1 = sl1[0], LH = slh[0];
#pragma unroll
        for (int w = 1; w < 4; ++w) {
            float mn = fmaxf(M, sm[w]);
            L1 = L1 * __expf(M - mn) + sl1[w] * __expf(sm[w] - mn);
            LH = LH * __expf(0.5f * (M - mn)) + slh[w] * __expf(0.5f * (sm[w] - mn));
            M = mn;
        }
        if (lse1) lse1[r] = M + __logf(L1);
        lseh[r] = 0.5f * M + __logf(LH);
    }
}

__global__ void zero_accum_kernel(double* accum) {
    accum[0] = 0.0; accum[1] = 0.0;
}

__global__ __launch_bounds__(256)
void loss_kernel(const float* __restrict__ S, const float* __restrict__ Tm,
                 const float* __restrict__ lse_s1, const float* __restrict__ lse_s2,
                 const float* __restrict__ lse_t2, const int* __restrict__ tgt,
                 double* __restrict__ accum, int V)
{
    const int r = blockIdx.x;
    const float ls1 = lse_s1[r], ls2 = lse_s2[r], lt2 = lse_t2[r];
    const float* s = S  + (size_t)r * V;
    const float* t = Tm + (size_t)r * V;
    const int tid = threadIdx.x;

    float local = 0.f;
    for (int v = tid * 4; v < V; v += 1024) {
        float4 sv = *reinterpret_cast<const float4*>(&s[v]);
        float4 tv = *reinterpret_cast<const float4*>(&t[v]);
        const float* sp_ = (const float*)&sv;
        const float* tp_ = (const float*)&tv;
#pragma unroll
        for (int j = 0; j < 4; ++j) {
            float sp = 0.5f * sp_[j] - ls2;       // log_softmax(s/T)
            float tp = 0.5f * tp_[j] - lt2;       // log_softmax(t/T)
            float p = __expf(sp), q = __expf(tp);
            float mm = 0.5f * (p + q);
            float lm = __logf(fmaxf(mm, 1e-38f));
            local += 0.5f * (p * (sp - lm) + q * (tp - lm));
        }
    }
#pragma unroll
    for (int off = 32; off > 0; off >>= 1)
        local += __shfl_xor(local, off);
    __shared__ float ls[4];
    if ((tid & 63) == 0) ls[tid >> 6] = local;
    __syncthreads();
    if (tid == 0) {
        float blocksum = ls[0] + ls[1] + ls[2] + ls[3];
        atomicAdd(&accum[1], (double)blocksum);
        int tg = tgt[r];
        if (tg != -100) {
            float nll = -(s[tg] - ls1);   // CE on un-tempered logits
            atomicAdd(&accum[0], (double)nll);
        }
    }
}

__global__ void finalize_kernel(const double* __restrict__ accum,
                                float* __restrict__ out, double inv_n) {
    // 0.5 * hard + 0.5 * soft, each sum/N
    out[0] = (float)(0.5 * (accum[0] * inv_n) + 0.5 * (accum[1] * inv_n));
}

extern "C" void kernel_launch(void* const* d_in, const int* in_sizes, int n_in,
                              void* d_out, int out_size, void* d_ws, size_t ws_size,
                              hipStream_t stream)
{
    const float* s_in = (const float*)d_in[0];   // [N, 2048]
    const float* s_w  = (const float*)d_in[1];   // [V, 2048]
    const float* s_b  = (const float*)d_in[2];   // [V]
    const float* t_in = (const float*)d_in[3];   // [N, 4096]
    const float* t_w  = (const float*)d_in[4];   // [V, 4096]
    const float* t_b  = (const float*)d_in[5];   // [V]
    const int*   tgt  = (const int*)d_in[6];     // [N]

    const int N = 2048, V = 32000, KS = 2048, KT = 4096;

    char* ws = (char*)d_ws;
    double* accum  = (double*)ws;                 // 16 B
    float* lse_s1  = (float*)(ws + 64);
    float* lse_s2  = lse_s1 + N;
    float* lse_t2  = lse_s2 + N;
    float* s_log   = (float*)(ws + 32768);                 // 2048*32000 fp32 = 262.1 MB
    float* t_log   = s_log + (size_t)N * V;                // 524.3 MB

    zero_accum_kernel<<<1, 1, 0, stream>>>(accum);

    dim3 gblk(V / BN, N / BM);   // (250, 16)
    gemm_bt_kernel<<<gblk, 256, 0, stream>>>(s_in, s_w, s_b, s_log, KS, V);
    gemm_bt_kernel<<<gblk, 256, 0, stream>>>(t_in, t_w, t_b, t_log, KT, V);

    rowstats_kernel<<<N, 256, 0, stream>>>(s_log, V, lse_s1, lse_s2);
    rowstats_kernel<<<N, 256, 0, stream>>>(t_log, V, nullptr, lse_t2);

    loss_kernel<<<N, 256, 0, stream>>>(s_log, t_log, lse_s1, lse_s2, lse_t2, tgt, accum, V);
    finalize_kernel<<<1, 1, 0, stream>>>(accum, (float*)d_out, 1.0 / (double)N);
}

// Round 2
// 1713.851 us; speedup vs baseline: 1.3593x; 1.3593x over previous
//
#include <hip/hip_runtime.h>
#include <hip/hip_bf16.h>
#include <cstdint>
#include <cstddef>

typedef __attribute__((ext_vector_type(8))) short short8v;
typedef __attribute__((ext_vector_type(4))) short short4v;
typedef __attribute__((ext_vector_type(4))) float f32x4;

__device__ __forceinline__ short f2bf(float f) {
    union { float f; unsigned u; } c; c.f = f;
    unsigned r = c.u + 0x7FFFu + ((c.u >> 16) & 1u);
    return (short)(r >> 16);
}

__device__ __forceinline__ void load_lds_16B(const void* g, void* l) {
    __builtin_amdgcn_global_load_lds(
        (const __attribute__((address_space(1))) void*)g,
        (__attribute__((address_space(3))) void*)l, 16, 0, 0);
}

// ---------------- fp32 -> bf16 convert (vectorized) ----------------
__global__ __launch_bounds__(256)
void cvt_kernel(const float* __restrict__ in, ushort* __restrict__ out, size_t n8)
{
    size_t stride = (size_t)gridDim.x * blockDim.x;
    for (size_t i = (size_t)blockIdx.x * blockDim.x + threadIdx.x; i < n8; i += stride) {
        const float4* p = reinterpret_cast<const float4*>(in + i * 8);
        float4 a = p[0], b = p[1];
        short8v o = { f2bf(a.x), f2bf(a.y), f2bf(a.z), f2bf(a.w),
                      f2bf(b.x), f2bf(b.y), f2bf(b.z), f2bf(b.w) };
        *reinterpret_cast<short8v*>(out + i * 8) = o;
    }
}

// ---------------- m97-structure bf16 GEMM ----------------
// C[row,col] = sum_k A[row,k]*W[col,k] + bias[col].  A:[MxK] bf16, W:[VxK] bf16.
// 1D grid = (V/128)*(M/128), M/128 == 16 hardcoded. XCD-bijective swizzle,
// panel-major order (16 consecutive wgids share one W panel).
__global__ __launch_bounds__(256)
void gemm_bf16_kernel(const ushort* __restrict__ A, const ushort* __restrict__ W,
                      const float* __restrict__ bias, float* __restrict__ C,
                      int K, int V)
{
    __shared__ ushort As[128 * 64];
    __shared__ ushort Bs[128 * 64];

    const int tid  = threadIdx.x;
    const int lane = tid & 63;
    const int wave = tid >> 6;

    // bijective XCD swizzle (gridDim.x % 8 == 0 guaranteed: 4000)
    const int cpx  = gridDim.x >> 3;
    const int wgid = (blockIdx.x & 7) * cpx + (blockIdx.x >> 3);
    const int row0 = (wgid & 15) * 128;
    const int col0 = (wgid >> 4) * 128;

    const int wr = wave >> 1;
    const int wc = wave & 1;

    f32x4 acc[4][4];
#pragma unroll
    for (int m = 0; m < 4; ++m)
#pragma unroll
        for (int n = 0; n < 4; ++n)
            acc[m][n] = (f32x4)(0.0f);

    // staging: call i stages rows i*32 + wave*8 .. +7 ; lane -> row (lane>>3), col (lane&7)*8
    const int srow = lane >> 3;
    const int scol = (lane & 7) * 8;
    const ushort* a_src = A + (size_t)(row0 + wave * 8 + srow) * K + scol;
    const ushort* w_src = W + (size_t)(col0 + wave * 8 + srow) * K + scol;
    ushort* as_dst = As + (wave * 8) * 64;
    ushort* bs_dst = Bs + (wave * 8) * 64;

    const int lrow = lane & 15;
    const int fcol = (lane >> 4) * 8;

    for (int k0 = 0; k0 < K; k0 += 64) {
        __syncthreads();
#pragma unroll
        for (int i = 0; i < 4; ++i) {
            load_lds_16B(a_src + (size_t)i * 32 * K + k0, as_dst + i * 32 * 64);
            load_lds_16B(w_src + (size_t)i * 32 * K + k0, bs_dst + i * 32 * 64);
        }
        __syncthreads();   // compiler drains vmcnt(0) here (m97 structure)

#pragma unroll
        for (int kk = 0; kk < 2; ++kk) {
            short8v af[4], bf[4];
#pragma unroll
            for (int m = 0; m < 4; ++m)
                af[m] = *reinterpret_cast<const short8v*>(
                    &As[(wr * 64 + m * 16 + lrow) * 64 + kk * 32 + fcol]);
#pragma unroll
            for (int n = 0; n < 4; ++n)
                bf[n] = *reinterpret_cast<const short8v*>(
                    &Bs[(wc * 64 + n * 16 + lrow) * 64 + kk * 32 + fcol]);
#pragma unroll
            for (int m = 0; m < 4; ++m)
#pragma unroll
                for (int n = 0; n < 4; ++n)
                    acc[m][n] = __builtin_amdgcn_mfma_f32_16x16x32_bf16(af[m], bf[n], acc[m][n], 0, 0, 0);
        }
    }

    // epilogue: C/D layout col = lane&15, row = (lane>>4)*4 + j  [m89]
    const int crow_base = row0 + wr * 64 + (lane >> 4) * 4;
    const int ccol_base = col0 + wc * 64 + lrow;
#pragma unroll
    for (int m = 0; m < 4; ++m) {
#pragma unroll
        for (int n = 0; n < 4; ++n) {
            int gc = ccol_base + n * 16;
            float b = bias[gc];
#pragma unroll
            for (int j = 0; j < 4; ++j) {
                int gr = crow_base + m * 16 + j;
                C[(size_t)gr * V + gc] = acc[m][n][j] + b;
            }
        }
    }
}

// ---------------- fallback GEMM (fused fp32->bf16 convert), round-1 ----------------
#define BM 128
#define BN 128
#define BK 32
#define LDS_STRIDE 40

__global__ __launch_bounds__(256)
void gemm_bt_kernel(const float* __restrict__ A, const float* __restrict__ W,
                    const float* __restrict__ bias, float* __restrict__ C,
                    int K, int V)
{
    __shared__ short As[BM][LDS_STRIDE];
    __shared__ short Bs[BN][LDS_STRIDE];

    const int tid  = threadIdx.x;
    const int lane = tid & 63;
    const int wave = tid >> 6;
    const int wr = wave >> 1;
    const int wc = wave & 1;

    const int row0 = blockIdx.y * BM;
    const int col0 = blockIdx.x * BN;

    f32x4 acc[4][4];
#pragma unroll
    for (int m = 0; m < 4; ++m)
#pragma unroll
        for (int n = 0; n < 4; ++n)
            acc[m][n] = (f32x4)(0.0f);

    const int lrow = lane & 15;
    const int kblk = (lane >> 4) * 8;

    for (int k0 = 0; k0 < K; k0 += BK) {
        __syncthreads();
#pragma unroll
        for (int i = 0; i < 4; ++i) {
            int idx = tid + i * 256;
            int r   = idx >> 3;
            int c4  = (idx & 7) * 4;
            float4 va = *reinterpret_cast<const float4*>(&A[(size_t)(row0 + r) * K + k0 + c4]);
            short4v ha = { f2bf(va.x), f2bf(va.y), f2bf(va.z), f2bf(va.w) };
            *reinterpret_cast<short4v*>(&As[r][c4]) = ha;
            float4 vb = *reinterpret_cast<const float4*>(&W[(size_t)(col0 + r) * K + k0 + c4]);
            short4v hb = { f2bf(vb.x), f2bf(vb.y), f2bf(vb.z), f2bf(vb.w) };
            *reinterpret_cast<short4v*>(&Bs[r][c4]) = hb;
        }
        __syncthreads();

        short8v af[4], bfr[4];
#pragma unroll
        for (int m = 0; m < 4; ++m)
            af[m] = *reinterpret_cast<const short8v*>(&As[wr * 64 + m * 16 + lrow][kblk]);
#pragma unroll
        for (int n = 0; n < 4; ++n)
            bfr[n] = *reinterpret_cast<const short8v*>(&Bs[wc * 64 + n * 16 + lrow][kblk]);
#pragma unroll
        for (int m = 0; m < 4; ++m)
#pragma unroll
            for (int n = 0; n < 4; ++n)
                acc[m][n] = __builtin_amdgcn_mfma_f32_16x16x32_bf16(af[m], bfr[n], acc[m][n], 0, 0, 0);
    }

    const int crow_base = row0 + wr * 64 + (lane >> 4) * 4;
    const int ccol_base = col0 + wc * 64 + lrow;
#pragma unroll
    for (int m = 0; m < 4; ++m) {
#pragma unroll
        for (int n = 0; n < 4; ++n) {
            int gc = ccol_base + n * 16;
            float b = bias[gc];
#pragma unroll
            for (int j = 0; j < 4; ++j) {
                int gr = crow_base + m * 16 + j;
                C[(size_t)gr * V + gc] = acc[m][n][j] + b;
            }
        }
    }
}

// ---------------- fused row stats + loss ----------------
__global__ void zero_accum_kernel(double* accum) {
    accum[0] = 0.0; accum[1] = 0.0;
}

__global__ __launch_bounds__(1024)
void stats_loss_kernel(const float* __restrict__ S, const float* __restrict__ Tm,
                       const int* __restrict__ tgt, double* __restrict__ accum, int V)
{
    const int r = blockIdx.x;
    const float* s = S  + (size_t)r * V;
    const float* t = Tm + (size_t)r * V;
    const int tid = threadIdx.x;

    // ---- pass 1: online stats (student max ms serves T=1 and T=2; teacher mt, T=2) ----
    float ms = -1e30f, l1 = 0.f, lh = 0.f;
    float mt = -1e30f, lt = 0.f;
    for (int v = tid * 4; v < V; v += 4096) {
        float4 sv = *reinterpret_cast<const float4*>(&s[v]);
        float4 tv = *reinterpret_cast<const float4*>(&t[v]);
        const float* sp = (const float*)&sv;
        const float* tp = (const float*)&tv;
#pragma unroll
        for (int j = 0; j < 4; ++j) {
            float a = sp[j];
            if (a > ms) {
                float d = ms - a;
                l1 *= __expf(d);
                lh *= __expf(0.5f * d);
                ms = a;
            }
            l1 += __expf(a - ms);
            lh += __expf(0.5f * (a - ms));
            float b = tp[j];
            if (b > mt) {
                lt *= __expf(0.5f * (mt - b));
                mt = b;
            }
            lt += __expf(0.5f * (b - mt));
        }
    }
#pragma unroll
    for (int off = 32; off > 0; off >>= 1) {
        float mso = __shfl_xor(ms, off), l1o = __shfl_xor(l1, off), lho = __shfl_xor(lh, off);
        float mn = fmaxf(ms, mso);
        l1 = l1 * __expf(ms - mn) + l1o * __expf(mso - mn);
        lh = lh * __expf(0.5f * (ms - mn)) + lho * __expf(0.5f * (mso - mn));
        ms = mn;
        float mto = __shfl_xor(mt, off), lto = __shfl_xor(lt, off);
        float mn2 = fmaxf(mt, mto);
        lt = lt * __expf(0.5f * (mt - mn2)) + lto * __expf(0.5f * (mto - mn2));
        mt = mn2;
    }
    __shared__ float red[16][5];
    __shared__ float bc[3];
    if ((tid & 63) == 0) {
        int w = tid >> 6;
        red[w][0] = ms; red[w][1] = l1; red[w][2] = lh;
        red[w][3] = mt; red[w][4] = lt;
    }
    __syncthreads();
    if (tid == 0) {
        float M = red[0][0], L1 = red[0][1], LH = red[0][2];
        float Mt = red[0][3], Lt = red[0][4];
#pragma unroll
        for (int w = 1; w < 16; ++w) {
            float mn = fmaxf(M, red[w][0]);
            L1 = L1 * __expf(M - mn) + red[w][1] * __expf(red[w][0] - mn);
            LH = LH * __expf(0.5f * (M - mn)) + red[w][2] * __expf(0.5f * (red[w][0] - mn));
            M = mn;
            float mn2 = fmaxf(Mt, red[w][3]);
            Lt = Lt * __expf(0.5f * (Mt - mn2)) + red[w][4] * __expf(0.5f * (red[w][3] - mn2));
            Mt = mn2;
        }
        bc[0] = M + __logf(L1);             // lse_s (T=1)
        bc[1] = 0.5f * M + __logf(LH);      // lse_s (T=2)
        bc[2] = 0.5f * Mt + __logf(Lt);     // lse_t (T=2)
    }
    __syncthreads();
    const float ls1 = bc[0], ls2 = bc[1], lt2 = bc[2];

    // ---- pass 2: JSD (rows should be L3-resident) ----
    float local = 0.f;
    for (int v = tid * 4; v < V; v += 4096) {
        float4 sv = *reinterpret_cast<const float4*>(&s[v]);
        float4 tv = *reinterpret_cast<const float4*>(&t[v]);
        const float* sp_ = (const float*)&sv;
        const float* tp_ = (const float*)&tv;
#pragma unroll
        for (int j = 0; j < 4; ++j) {
            float sp = 0.5f * sp_[j] - ls2;
            float tp = 0.5f * tp_[j] - lt2;
            float p = __expf(sp), q = __expf(tp);
            float mm = 0.5f * (p + q);
            float lm = __logf(fmaxf(mm, 1e-38f));
            local += 0.5f * (p * (sp - lm) + q * (tp - lm));
        }
    }
#pragma unroll
    for (int off = 32; off > 0; off >>= 1)
        local += __shfl_xor(local, off);
    __shared__ float ls[16];
    if ((tid & 63) == 0) ls[tid >> 6] = local;
    __syncthreads();
    if (tid == 0) {
        float blocksum = 0.f;
#pragma unroll
        for (int w = 0; w < 16; ++w) blocksum += ls[w];
        atomicAdd(&accum[1], (double)blocksum);
        int tg = tgt[r];
        if (tg != -100) {
            float nll = -(s[tg] - ls1);
            atomicAdd(&accum[0], (double)nll);
        }
    }
}

__global__ void finalize_kernel(const double* __restrict__ accum,
                                float* __restrict__ out, double inv_n) {
    out[0] = (float)(0.5 * (accum[0] * inv_n) + 0.5 * (accum[1] * inv_n));
}

extern "C" void kernel_launch(void* const* d_in, const int* in_sizes, int n_in,
                              void* d_out, int out_size, void* d_ws, size_t ws_size,
                              hipStream_t stream)
{
    const float* s_in = (const float*)d_in[0];   // [N, 2048]
    const float* s_w  = (const float*)d_in[1];   // [V, 2048]
    const float* s_b  = (const float*)d_in[2];   // [V]
    const float* t_in = (const float*)d_in[3];   // [N, 4096]
    const float* t_w  = (const float*)d_in[4];   // [V, 4096]
    const float* t_b  = (const float*)d_in[5];   // [V]
    const int*   tgt  = (const int*)d_in[6];     // [N]

    const int N = 2048, V = 32000, KS = 2048, KT = 4096;

    const size_t e_sin = (size_t)N * KS;          // 4,194,304
    const size_t e_sw  = (size_t)V * KS;          // 65,536,000
    const size_t e_tin = (size_t)N * KT;          // 8,388,608
    const size_t e_tw  = (size_t)V * KT;          // 131,072,000
    const size_t bf16_bytes  = 2 * (e_sin + e_sw + e_tin + e_tw);  // 418,381,824 (4096-mult)
    const size_t logit_bytes = 2 * (size_t)N * V * 4;              // 524,288,000
    const size_t need = 4096 + bf16_bytes + logit_bytes;

    char* ws = (char*)d_ws;
    double* accum = (double*)ws;

    zero_accum_kernel<<<1, 1, 0, stream>>>(accum);

    if (ws_size >= need) {
        ushort* s_in_b = (ushort*)(ws + 4096);
        ushort* s_w_b  = s_in_b + e_sin;
        ushort* t_in_b = s_w_b + e_sw;
        ushort* t_w_b  = t_in_b + e_tin;
        float*  s_log  = (float*)(ws + 4096 + bf16_bytes);
        float*  t_log  = s_log + (size_t)N * V;

        cvt_kernel<<<512,  256, 0, stream>>>(s_in, s_in_b, e_sin / 8);
        cvt_kernel<<<2048, 256, 0, stream>>>(s_w,  s_w_b,  e_sw  / 8);
        cvt_kernel<<<1024, 256, 0, stream>>>(t_in, t_in_b, e_tin / 8);
        cvt_kernel<<<2048, 256, 0, stream>>>(t_w,  t_w_b,  e_tw  / 8);

        const int grid = (V / 128) * (N / 128);   // 4000, %8==0
        gemm_bf16_kernel<<<grid, 256, 0, stream>>>(s_in_b, s_w_b, s_b, s_log, KS, V);
        gemm_bf16_kernel<<<grid, 256, 0, stream>>>(t_in_b, t_w_b, t_b, t_log, KT, V);

        stats_loss_kernel<<<N, 1024, 0, stream>>>(s_log, t_log, tgt, accum, V);
    } else {
        float* s_log = (float*)(ws + 4096);
        float* t_log = s_log + (size_t)N * V;

        dim3 gblk(V / BN, N / BM);
        gemm_bt_kernel<<<gblk, 256, 0, stream>>>(s_in, s_w, s_b, s_log, KS, V);
        gemm_bt_kernel<<<gblk, 256, 0, stream>>>(t_in, t_w, t_b, t_log, KT, V);

        stats_loss_kernel<<<N, 1024, 0, stream>>>(s_log, t_log, tgt, accum, V);
    }

    finalize_kernel<<<1, 1, 0, stream>>>(accum, (float*)d_out, 1.0 / (double)N);
}

// Round 3
// 1099.769 us; speedup vs baseline: 2.1182x; 1.5584x over previous
//
#include <hip/hip_runtime.h>
#include <hip/hip_bf16.h>
#include <cstdint>
#include <cstddef>

typedef __attribute__((ext_vector_type(8))) short short8v;
typedef __attribute__((ext_vector_type(4))) short short4v;
typedef __attribute__((ext_vector_type(4))) float f32x4;

__device__ __forceinline__ short f2bf(float f) {
    union { float f; unsigned u; } c; c.f = f;
    unsigned r = c.u + 0x7FFFu + ((c.u >> 16) & 1u);
    return (short)(r >> 16);
}

__device__ __forceinline__ void load_lds_16B(const void* g, void* l) {
    __builtin_amdgcn_global_load_lds(
        (const __attribute__((address_space(1))) void*)g,
        (__attribute__((address_space(3))) void*)l, 16, 0, 0);
}

// ---------------- fp32 -> bf16 convert (vectorized) ----------------
__global__ __launch_bounds__(256)
void cvt_kernel(const float* __restrict__ in, ushort* __restrict__ out, size_t n8)
{
    size_t stride = (size_t)gridDim.x * blockDim.x;
    for (size_t i = (size_t)blockIdx.x * blockDim.x + threadIdx.x; i < n8; i += stride) {
        const float4* p = reinterpret_cast<const float4*>(in + i * 8);
        float4 a = p[0], b = p[1];
        short8v o = { f2bf(a.x), f2bf(a.y), f2bf(a.z), f2bf(a.w),
                      f2bf(b.x), f2bf(b.y), f2bf(b.z), f2bf(b.w) };
        *reinterpret_cast<short8v*>(out + i * 8) = o;
    }
}

// ---------------- 256x256 8-phase bf16 GEMM (T1+T2+T3+T4+T5) ----------------
// C[row,col] = sum_k A[row,k]*W[col,k] + bias[col]. A:[2048xK] bf16, W:[VxK] bf16.
// 512 threads = 8 waves (2M x 4N). LDS 128 KiB: A dbuf 2x32KB + B dbuf 2x32KB.
// K-tile = 64. Per iter: compute tiles 2i (buf0, ph1-4) and 2i+1 (buf1, ph5-8).
// Stage slots: ph1: A(2i+1) both halves; ph3/ph4: B(2i+2) h0/h1; ph5: A(2i+2)
// both halves; ph6/ph7: B(2i+3) h0/h1.  vmcnt(4) before closing barrier of
// ph4/ph8 forces the next-needed tile landed while keeping 4 loads in flight.
// T2 swizzle: logical 16B-col c16 lives at physical c16 ^ (row&7); applied as
// inverse-swizzled GLOBAL source + linear LDS dest (global_load_lds constraint)
// + swizzled ds_read address.

#define SEG_A0 0
#define SEG_A1 16384
#define SEG_B0 32768
#define SEG_B1 49152

#define READ_B_ALL(bseg) do {                                                  \
    _Pragma("unroll")                                                          \
    for (int nf = 0; nf < 4; ++nf) {                                           \
        const int rb = (bseg) + brow + nf * 1024;                              \
        bfr[nf][0] = *(const short8v*)&sh[rb + c16a];                          \
        bfr[nf][1] = *(const short8v*)&sh[rb + c16b];                          \
    }                                                                          \
} while (0)

#define READ_A2(aseg, mfb) do {                                                \
    _Pragma("unroll")                                                          \
    for (int d = 0; d < 2; ++d) {                                              \
        const int ra = (aseg) + arow + ((mfb) + d) * 1024;                     \
        af[d][0] = *(const short8v*)&sh[ra + c16a];                            \
        af[d][1] = *(const short8v*)&sh[ra + c16b];                            \
    }                                                                          \
} while (0)

#define MFMA16(mfb) do {                                                       \
    __builtin_amdgcn_s_setprio(1);                                             \
    _Pragma("unroll")                                                          \
    for (int d = 0; d < 2; ++d) {                                              \
        _Pragma("unroll")                                                      \
        for (int nf = 0; nf < 4; ++nf) {                                       \
            acc[(mfb)+d][nf] = __builtin_amdgcn_mfma_f32_16x16x32_bf16(        \
                af[d][0], bfr[nf][0], acc[(mfb)+d][nf], 0, 0, 0);              \
            acc[(mfb)+d][nf] = __builtin_amdgcn_mfma_f32_16x16x32_bf16(        \
                af[d][1], bfr[nf][1], acc[(mfb)+d][nf], 0, 0, 0);              \
        }                                                                      \
    }                                                                          \
    __builtin_amdgcn_s_setprio(0);                                             \
} while (0)

#define BAR() __builtin_amdgcn_s_barrier()
#define VMCNT4() asm volatile("s_waitcnt vmcnt(4)" ::: "memory")
#define VMCNT0() asm volatile("s_waitcnt vmcnt(0)" ::: "memory")

__global__ __launch_bounds__(512, 2)
void gemm256_kernel(const ushort* __restrict__ A, const ushort* __restrict__ W,
                    const float* __restrict__ bias, float* __restrict__ C,
                    int K, int V)
{
    __shared__ ushort sh[65536];   // 128 KiB

    const int tid  = threadIdx.x;
    const int lane = tid & 63;
    const int wave = tid >> 6;
    const int wm = wave >> 2;      // 0..1
    const int wn = wave & 3;       // 0..3

    // T1: bijective XCD swizzle (grid 1000, %8==0); panel-major: 8 row-blocks
    // sharing a W panel are consecutive within an XCD chunk.
    const int cpx = gridDim.x >> 3;
    const int wg  = ((int)blockIdx.x & 7) * cpx + ((int)blockIdx.x >> 3);
    const int row0 = (wg & 7) * 256;
    const int col0 = (wg >> 3) * 256;

    const int NT = K >> 6;         // K-tiles
    const int NI = NT >> 1;        // iters (2 tiles each)

    // staging addressing: thread t covers row (t>>3) of a 64-row round,
    // 16B col block (t&7), with inverse swizzle on the GLOBAL column.
    const int sr = lane >> 3;                  // 0..7
    const int sc = ((lane & 7) ^ sr) * 8;      // swizzled col (ushorts)
    const size_t a_off = (size_t)(row0 + wave * 8 + sr) * K + sc;
    const size_t w_off = (size_t)(col0 + wave * 8 + sr) * K + sc;
    const int lds_u = wave * 8 * 64;           // per-wave LDS base (ushorts)

    auto stage_half = [&](const ushort* gb, size_t goff, int seg, int h, int k0) {
        const ushort* g0 = gb + goff + (size_t)(h * 128) * K + k0;
        load_lds_16B(g0,                   &sh[seg + (h * 128     ) * 64 + lds_u]);
        load_lds_16B(g0 + (size_t)64 * K,  &sh[seg + (h * 128 + 64) * 64 + lds_u]);
    };

    // fragment-read addressing (swizzled ds_read): row&7 == lane&7 for all frags
    const int l15  = lane & 15;
    const int c16a = (((lane >> 4)    ) ^ (lane & 7)) * 8;
    const int c16b = (((lane >> 4) + 4) ^ (lane & 7)) * 8;
    const int arow = (wm * 128 + l15) * 64;
    const int brow = (wn * 64  + l15) * 64;

    f32x4 acc[8][4];
#pragma unroll
    for (int m = 0; m < 8; ++m)
#pragma unroll
        for (int n = 0; n < 4; ++n)
            acc[m][n] = (f32x4)(0.0f);

    short8v bfr[4][2];
    short8v af[2][2];

    // ---- prologue: A(T0), B(T0), B(T1); force T0 landed, keep B(T1) in flight
    stage_half(A, a_off, SEG_A0, 0, 0);
    stage_half(A, a_off, SEG_A0, 1, 0);
    stage_half(W, w_off, SEG_B0, 0, 0);
    stage_half(W, w_off, SEG_B0, 1, 0);
    stage_half(W, w_off, SEG_B1, 0, 64);
    stage_half(W, w_off, SEG_B1, 1, 64);
    VMCNT4();
    BAR();

    // ---- main loop: iters 0 .. NI-2 (full), last iter as tail below
    for (int i = 0; i < NI - 1; ++i) {
        const int kA1 = (2 * i + 1) * 64;
        const int kN2 = (2 * i + 2) * 64;
        const int kB3 = (2 * i + 3) * 64;

        // ph1: B-all + A mf0,1 from buf0; stage A(2i+1) -> A1 (both halves)
        READ_B_ALL(SEG_B0); READ_A2(SEG_A0, 0);
        stage_half(A, a_off, SEG_A1, 0, kA1);
        stage_half(A, a_off, SEG_A1, 1, kA1);
        BAR(); MFMA16(0); BAR();
        // ph2
        READ_A2(SEG_A0, 2);
        BAR(); MFMA16(2); BAR();
        // ph3: stage B(2i+2) h0 -> B0 (B0 reads finished at ph1)
        READ_A2(SEG_A0, 4);
        stage_half(W, w_off, SEG_B0, 0, kN2);
        BAR(); MFMA16(4); BAR();
        // ph4: stage B(2i+2) h1; vmcnt(4) forces tile 2i+1 fully landed
        READ_A2(SEG_A0, 6);
        stage_half(W, w_off, SEG_B0, 1, kN2);
        BAR(); MFMA16(6);
        VMCNT4();
        BAR();
        // ph5: B-all + A mf0,1 from buf1; stage A(2i+2) -> A0 (A0 reads done ph4)
        READ_B_ALL(SEG_B1); READ_A2(SEG_A1, 0);
        stage_half(A, a_off, SEG_A0, 0, kN2);
        stage_half(A, a_off, SEG_A0, 1, kN2);
        BAR(); MFMA16(0); BAR();
        // ph6: stage B(2i+3) h0 -> B1 (B1 reads finished at ph5)
        READ_A2(SEG_A1, 2);
        stage_half(W, w_off, SEG_B1, 0, kB3);
        BAR(); MFMA16(2); BAR();
        // ph7: stage B(2i+3) h1
        READ_A2(SEG_A1, 4);
        stage_half(W, w_off, SEG_B1, 1, kB3);
        BAR(); MFMA16(4); BAR();
        // ph8: vmcnt(4) forces tile 2i+2 fully landed for next iter
        READ_A2(SEG_A1, 6);
        BAR(); MFMA16(6);
        VMCNT4();
        BAR();
    }

    // ---- tail iter (tiles NT-2, NT-1): only A(NT-1) still needs staging
    {
        const int kA1 = (NT - 1) * 64;
        READ_B_ALL(SEG_B0); READ_A2(SEG_A0, 0);
        stage_half(A, a_off, SEG_A1, 0, kA1);
        stage_half(A, a_off, SEG_A1, 1, kA1);
        BAR(); MFMA16(0); BAR();
        READ_A2(SEG_A0, 2); BAR(); MFMA16(2); BAR();
        READ_A2(SEG_A0, 4); BAR(); MFMA16(4); BAR();
        READ_A2(SEG_A0, 6); BAR(); MFMA16(6);
        VMCNT0();
        BAR();
        READ_B_ALL(SEG_B1); READ_A2(SEG_A1, 0); BAR(); MFMA16(0); BAR();
        READ_A2(SEG_A1, 2); BAR(); MFMA16(2); BAR();
        READ_A2(SEG_A1, 4); BAR(); MFMA16(4); BAR();
        READ_A2(SEG_A1, 6); BAR(); MFMA16(6);
    }

    // ---- epilogue: C/D layout col = lane&15, row = (lane>>4)*4 + j  [m89]
    float bb[4];
#pragma unroll
    for (int nf = 0; nf < 4; ++nf)
        bb[nf] = bias[col0 + wn * 64 + nf * 16 + l15];

#pragma unroll
    for (int mf = 0; mf < 8; ++mf) {
        const int gr = row0 + wm * 128 + mf * 16 + (lane >> 4) * 4;
#pragma unroll
        for (int nf = 0; nf < 4; ++nf) {
            const int gc = col0 + wn * 64 + nf * 16 + l15;
#pragma unroll
            for (int j = 0; j < 4; ++j)
                C[(size_t)(gr + j) * V + gc] = acc[mf][nf][j] + bb[nf];
        }
    }
}

// ---------------- fallback GEMM (fused fp32->bf16 convert) ----------------
#define BM 128
#define BN 128
#define BK 32
#define LDS_STRIDE 40

__global__ __launch_bounds__(256)
void gemm_bt_kernel(const float* __restrict__ A, const float* __restrict__ W,
                    const float* __restrict__ bias, float* __restrict__ C,
                    int K, int V)
{
    __shared__ short As[BM][LDS_STRIDE];
    __shared__ short Bs[BN][LDS_STRIDE];

    const int tid  = threadIdx.x;
    const int lane = tid & 63;
    const int wave = tid >> 6;
    const int wr = wave >> 1;
    const int wc = wave & 1;

    const int row0 = blockIdx.y * BM;
    const int col0 = blockIdx.x * BN;

    f32x4 acc[4][4];
#pragma unroll
    for (int m = 0; m < 4; ++m)
#pragma unroll
        for (int n = 0; n < 4; ++n)
            acc[m][n] = (f32x4)(0.0f);

    const int lrow = lane & 15;
    const int kblk = (lane >> 4) * 8;

    for (int k0 = 0; k0 < K; k0 += BK) {
        __syncthreads();
#pragma unroll
        for (int i = 0; i < 4; ++i) {
            int idx = tid + i * 256;
            int r   = idx >> 3;
            int c4  = (idx & 7) * 4;
            float4 va = *reinterpret_cast<const float4*>(&A[(size_t)(row0 + r) * K + k0 + c4]);
            short4v ha = { f2bf(va.x), f2bf(va.y), f2bf(va.z), f2bf(va.w) };
            *reinterpret_cast<short4v*>(&As[r][c4]) = ha;
            float4 vb = *reinterpret_cast<const float4*>(&W[(size_t)(col0 + r) * K + k0 + c4]);
            short4v hb = { f2bf(vb.x), f2bf(vb.y), f2bf(vb.z), f2bf(vb.w) };
            *reinterpret_cast<short4v*>(&Bs[r][c4]) = hb;
        }
        __syncthreads();

        short8v afv[4], bfv[4];
#pragma unroll
        for (int m = 0; m < 4; ++m)
            afv[m] = *reinterpret_cast<const short8v*>(&As[wr * 64 + m * 16 + lrow][kblk]);
#pragma unroll
        for (int n = 0; n < 4; ++n)
            bfv[n] = *reinterpret_cast<const short8v*>(&Bs[wc * 64 + n * 16 + lrow][kblk]);
#pragma unroll
        for (int m = 0; m < 4; ++m)
#pragma unroll
            for (int n = 0; n < 4; ++n)
                acc[m][n] = __builtin_amdgcn_mfma_f32_16x16x32_bf16(afv[m], bfv[n], acc[m][n], 0, 0, 0);
    }

    const int crow_base = row0 + wr * 64 + (lane >> 4) * 4;
    const int ccol_base = col0 + wc * 64 + lrow;
#pragma unroll
    for (int m = 0; m < 4; ++m) {
#pragma unroll
        for (int n = 0; n < 4; ++n) {
            int gc = ccol_base + n * 16;
            float b = bias[gc];
#pragma unroll
            for (int j = 0; j < 4; ++j) {
                int gr = crow_base + m * 16 + j;
                C[(size_t)gr * V + gc] = acc[m][n][j] + b;
            }
        }
    }
}

// ---------------- fused row stats + loss ----------------
__global__ void zero_accum_kernel(double* accum) {
    accum[0] = 0.0; accum[1] = 0.0;
}

__global__ __launch_bounds__(1024)
void stats_loss_kernel(const float* __restrict__ S, const float* __restrict__ Tm,
                       const int* __restrict__ tgt, double* __restrict__ accum, int V)
{
    const int r = blockIdx.x;
    const float* s = S  + (size_t)r * V;
    const float* t = Tm + (size_t)r * V;
    const int tid = threadIdx.x;

    float ms = -1e30f, l1 = 0.f, lh = 0.f;
    float mt = -1e30f, lt = 0.f;
    for (int v = tid * 4; v < V; v += 4096) {
        float4 sv = *reinterpret_cast<const float4*>(&s[v]);
        float4 tv = *reinterpret_cast<const float4*>(&t[v]);
        const float* sp = (const float*)&sv;
        const float* tp = (const float*)&tv;
#pragma unroll
        for (int j = 0; j < 4; ++j) {
            float a = sp[j];
            if (a > ms) {
                float d = ms - a;
                l1 *= __expf(d);
                lh *= __expf(0.5f * d);
                ms = a;
            }
            l1 += __expf(a - ms);
            lh += __expf(0.5f * (a - ms));
            float b = tp[j];
            if (b > mt) {
                lt *= __expf(0.5f * (mt - b));
                mt = b;
            }
            lt += __expf(0.5f * (b - mt));
        }
    }
#pragma unroll
    for (int off = 32; off > 0; off >>= 1) {
        float mso = __shfl_xor(ms, off), l1o = __shfl_xor(l1, off), lho = __shfl_xor(lh, off);
        float mn = fmaxf(ms, mso);
        l1 = l1 * __expf(ms - mn) + l1o * __expf(mso - mn);
        lh = lh * __expf(0.5f * (ms - mn)) + lho * __expf(0.5f * (mso - mn));
        ms = mn;
        float mto = __shfl_xor(mt, off), lto = __shfl_xor(lt, off);
        float mn2 = fmaxf(mt, mto);
        lt = lt * __expf(0.5f * (mt - mn2)) + lto * __expf(0.5f * (mto - mn2));
        mt = mn2;
    }
    __shared__ float red[16][5];
    __shared__ float bc[3];
    if ((tid & 63) == 0) {
        int w = tid >> 6;
        red[w][0] = ms; red[w][1] = l1; red[w][2] = lh;
        red[w][3] = mt; red[w][4] = lt;
    }
    __syncthreads();
    if (tid == 0) {
        float M = red[0][0], L1 = red[0][1], LH = red[0][2];
        float Mt = red[0][3], Lt = red[0][4];
#pragma unroll
        for (int w = 1; w < 16; ++w) {
            float mn = fmaxf(M, red[w][0]);
            L1 = L1 * __expf(M - mn) + red[w][1] * __expf(red[w][0] - mn);
            LH = LH * __expf(0.5f * (M - mn)) + red[w][2] * __expf(0.5f * (red[w][0] - mn));
            M = mn;
            float mn2 = fmaxf(Mt, red[w][3]);
            Lt = Lt * __expf(0.5f * (Mt - mn2)) + red[w][4] * __expf(0.5f * (red[w][3] - mn2));
            Mt = mn2;
        }
        bc[0] = M + __logf(L1);
        bc[1] = 0.5f * M + __logf(LH);
        bc[2] = 0.5f * Mt + __logf(Lt);
    }
    __syncthreads();
    const float ls1 = bc[0], ls2 = bc[1], lt2 = bc[2];

    float local = 0.f;
    for (int v = tid * 4; v < V; v += 4096) {
        float4 sv = *reinterpret_cast<const float4*>(&s[v]);
        float4 tv = *reinterpret_cast<const float4*>(&t[v]);
        const float* sp_ = (const float*)&sv;
        const float* tp_ = (const float*)&tv;
#pragma unroll
        for (int j = 0; j < 4; ++j) {
            float sp = 0.5f * sp_[j] - ls2;
            float tp = 0.5f * tp_[j] - lt2;
            float p = __expf(sp), q = __expf(tp);
            float mm = 0.5f * (p + q);
            float lm = __logf(fmaxf(mm, 1e-38f));
            local += 0.5f * (p * (sp - lm) + q * (tp - lm));
        }
    }
#pragma unroll
    for (int off = 32; off > 0; off >>= 1)
        local += __shfl_xor(local, off);
    __shared__ float ls[16];
    if ((tid & 63) == 0) ls[tid >> 6] = local;
    __syncthreads();
    if (tid == 0) {
        float blocksum = 0.f;
#pragma unroll
        for (int w = 0; w < 16; ++w) blocksum += ls[w];
        atomicAdd(&accum[1], (double)blocksum);
        int tg = tgt[r];
        if (tg != -100) {
            float nll = -(s[tg] - ls1);
            atomicAdd(&accum[0], (double)nll);
        }
    }
}

__global__ void finalize_kernel(const double* __restrict__ accum,
                                float* __restrict__ out, double inv_n) {
    out[0] = (float)(0.5 * (accum[0] * inv_n) + 0.5 * (accum[1] * inv_n));
}

extern "C" void kernel_launch(void* const* d_in, const int* in_sizes, int n_in,
                              void* d_out, int out_size, void* d_ws, size_t ws_size,
                              hipStream_t stream)
{
    const float* s_in = (const float*)d_in[0];   // [N, 2048]
    const float* s_w  = (const float*)d_in[1];   // [V, 2048]
    const float* s_b  = (const float*)d_in[2];   // [V]
    const float* t_in = (const float*)d_in[3];   // [N, 4096]
    const float* t_w  = (const float*)d_in[4];   // [V, 4096]
    const float* t_b  = (const float*)d_in[5];   // [V]
    const int*   tgt  = (const int*)d_in[6];     // [N]

    const int N = 2048, V = 32000, KS = 2048, KT = 4096;

    const size_t e_sin = (size_t)N * KS;
    const size_t e_sw  = (size_t)V * KS;
    const size_t e_tin = (size_t)N * KT;
    const size_t e_tw  = (size_t)V * KT;
    const size_t bf16_bytes  = 2 * (e_sin + e_sw + e_tin + e_tw);
    const size_t logit_bytes = 2 * (size_t)N * V * 4;
    const size_t need = 4096 + bf16_bytes + logit_bytes;

    char* ws = (char*)d_ws;
    double* accum = (double*)ws;

    zero_accum_kernel<<<1, 1, 0, stream>>>(accum);

    if (ws_size >= need) {
        ushort* s_in_b = (ushort*)(ws + 4096);
        ushort* s_w_b  = s_in_b + e_sin;
        ushort* t_in_b = s_w_b + e_sw;
        ushort* t_w_b  = t_in_b + e_tin;
        float*  s_log  = (float*)(ws + 4096 + bf16_bytes);
        float*  t_log  = s_log + (size_t)N * V;

        cvt_kernel<<<512,  256, 0, stream>>>(s_in, s_in_b, e_sin / 8);
        cvt_kernel<<<2048, 256, 0, stream>>>(s_w,  s_w_b,  e_sw  / 8);
        cvt_kernel<<<1024, 256, 0, stream>>>(t_in, t_in_b, e_tin / 8);
        cvt_kernel<<<2048, 256, 0, stream>>>(t_w,  t_w_b,  e_tw  / 8);

        const int grid = (V / 256) * (N / 256);   // 125 * 8 = 1000, %8==0
        gemm256_kernel<<<grid, 512, 0, stream>>>(s_in_b, s_w_b, s_b, s_log, KS, V);
        gemm256_kernel<<<grid, 512, 0, stream>>>(t_in_b, t_w_b, t_b, t_log, KT, V);

        stats_loss_kernel<<<N, 1024, 0, stream>>>(s_log, t_log, tgt, accum, V);
    } else {
        float* s_log = (float*)(ws + 4096);
        float* t_log = s_log + (size_t)N * V;

        dim3 gblk(V / BN, N / BM);
        gemm_bt_kernel<<<gblk, 256, 0, stream>>>(s_in, s_w, s_b, s_log, KS, V);
        gemm_bt_kernel<<<gblk, 256, 0, stream>>>(t_in, t_w, t_b, t_log, KT, V);

        stats_loss_kernel<<<N, 1024, 0, stream>>>(s_log, t_log, tgt, accum, V);
    }

    finalize_kernel<<<1, 1, 0, stream>>>(accum, (float*)d_out, 1.0 / (double)N);
}

// Round 4
// 1021.889 us; speedup vs baseline: 2.2797x; 1.0762x over previous
//
#include <hip/hip_runtime.h>
#include <hip/hip_bf16.h>
#include <cstdint>
#include <cstddef>

typedef __attribute__((ext_vector_type(8))) short short8v;
typedef __attribute__((ext_vector_type(4))) float f32x4;

__device__ __forceinline__ short f2bf(float f) {
    union { float f; unsigned u; } c; c.f = f;
    unsigned r = c.u + 0x7FFFu + ((c.u >> 16) & 1u);
    return (short)(r >> 16);
}

__device__ __forceinline__ float bf2f(ushort u) {
    union { unsigned u; float f; } c; c.u = ((unsigned)u) << 16;
    return c.f;
}

__device__ __forceinline__ void load_lds_16B(const void* g, void* l) {
    __builtin_amdgcn_global_load_lds(
        (const __attribute__((address_space(1))) void*)g,
        (__attribute__((address_space(3))) void*)l, 16, 0, 0);
}

// ---------------- fused fp32 -> bf16 convert of all 4 inputs ----------------
// Destinations are contiguous in ws; flat n8 index with cumulative bounds.
__global__ __launch_bounds__(256)
void cvt4_kernel(const float* __restrict__ s0, const float* __restrict__ s1,
                 const float* __restrict__ s2, const float* __restrict__ s3,
                 ushort* __restrict__ dst,
                 size_t c0, size_t c1, size_t c2, size_t c3)
{
    size_t stride = (size_t)gridDim.x * blockDim.x;
    for (size_t i = (size_t)blockIdx.x * blockDim.x + threadIdx.x; i < c3; i += stride) {
        const float* src; size_t off;
        if (i < c0)      { src = s0; off = i; }
        else if (i < c1) { src = s1; off = i - c0; }
        else if (i < c2) { src = s2; off = i - c1; }
        else             { src = s3; off = i - c2; }
        const float4* p = reinterpret_cast<const float4*>(src + off * 8);
        float4 a = p[0], b = p[1];
        short8v o = { f2bf(a.x), f2bf(a.y), f2bf(a.z), f2bf(a.w),
                      f2bf(b.x), f2bf(b.y), f2bf(b.z), f2bf(b.w) };
        *reinterpret_cast<short8v*>(dst + i * 8) = o;
    }
}

// ---------------- 256x256 8-phase bf16 GEMM (T1+T2+T3+T4+T5), bf16 C ----------------
// C[row,col] = bf16( sum_k A[row,k]*W[col,k] + bias[col] ).
// 512 threads = 8 waves (2M x 4N). LDS 128 KiB: A dbuf 2x32KB + B dbuf 2x32KB.
// Evened staging: 2 global_load_lds per phase.  Slots per iter:
//   ph1: A1h0  ph2: A1h1  ph3: B0'h0  ph4: B0'h1 [vmcnt(4)]
//   ph5: A0'h0 ph6: A0'h1 ph7: B1'h0  ph8: B1'h1 [vmcnt(4)]
// FIFO check (steady): at ph4, queue = [B1(4) A1(4) B0'(4)] -> vmcnt(4) drains
// B1+A1 = tile 2i+1 (read ph5-8).  At ph8, queue = [B0'(4) A0'(4) B1'(4)] ->
// vmcnt(4) drains B0'+A0' = tile 2i+2 (read next ph1-4).  Prologue stages
// A0,B0,B1 (12 loads), vmcnt(4).  Tail: stage A1_last at ph1/ph2, vmcnt(0) at ph4.
// T2 swizzle: 16B-col c16 at physical c16 ^ (row&7); inverse-swizzled GLOBAL
// source + linear LDS dest + swizzled ds_read (bank-conflict-free, verified r3).

#define SEG_A0 0
#define SEG_A1 16384
#define SEG_B0 32768
#define SEG_B1 49152

#define READ_B_ALL(bseg) do {                                                  \
    _Pragma("unroll")                                                          \
    for (int nf = 0; nf < 4; ++nf) {                                           \
        const int rb = (bseg) + brow + nf * 1024;                              \
        bfr[nf][0] = *(const short8v*)&sh[rb + c16a];                          \
        bfr[nf][1] = *(const short8v*)&sh[rb + c16b];                          \
    }                                                                          \
} while (0)

#define READ_A2(aseg, mfb) do {                                                \
    _Pragma("unroll")                                                          \
    for (int d = 0; d < 2; ++d) {                                              \
        const int ra = (aseg) + arow + ((mfb) + d) * 1024;                     \
        af[d][0] = *(const short8v*)&sh[ra + c16a];                            \
        af[d][1] = *(const short8v*)&sh[ra + c16b];                            \
    }                                                                          \
} while (0)

#define MFMA16(mfb) do {                                                       \
    __builtin_amdgcn_s_setprio(1);                                             \
    _Pragma("unroll")                                                          \
    for (int d = 0; d < 2; ++d) {                                              \
        _Pragma("unroll")                                                      \
        for (int nf = 0; nf < 4; ++nf) {                                       \
            acc[(mfb)+d][nf] = __builtin_amdgcn_mfma_f32_16x16x32_bf16(        \
                af[d][0], bfr[nf][0], acc[(mfb)+d][nf], 0, 0, 0);              \
            acc[(mfb)+d][nf] = __builtin_amdgcn_mfma_f32_16x16x32_bf16(        \
                af[d][1], bfr[nf][1], acc[(mfb)+d][nf], 0, 0, 0);              \
        }                                                                      \
    }                                                                          \
    __builtin_amdgcn_s_setprio(0);                                             \
} while (0)

#define BAR() __builtin_amdgcn_s_barrier()
#define VMCNT4() asm volatile("s_waitcnt vmcnt(4)" ::: "memory")
#define VMCNT0() asm volatile("s_waitcnt vmcnt(0)" ::: "memory")

__global__ __launch_bounds__(512, 2)
void gemm256_kernel(const ushort* __restrict__ A, const ushort* __restrict__ W,
                    const float* __restrict__ bias, ushort* __restrict__ C,
                    int K, int V)
{
    __shared__ ushort sh[65536];   // 128 KiB

    const int tid  = threadIdx.x;
    const int lane = tid & 63;
    const int wave = tid >> 6;
    const int wm = wave >> 2;      // 0..1
    const int wn = wave & 3;       // 0..3

    const int cpx = gridDim.x >> 3;
    const int wg  = ((int)blockIdx.x & 7) * cpx + ((int)blockIdx.x >> 3);
    const int row0 = (wg & 7) * 256;
    const int col0 = (wg >> 3) * 256;

    const int NT = K >> 6;
    const int NI = NT >> 1;

    const int sr = lane >> 3;
    const int sc = ((lane & 7) ^ sr) * 8;
    const size_t a_off = (size_t)(row0 + wave * 8 + sr) * K + sc;
    const size_t w_off = (size_t)(col0 + wave * 8 + sr) * K + sc;
    const int lds_u = wave * 8 * 64;

    auto stage_half = [&](const ushort* gb, size_t goff, int seg, int h, int k0) {
        const ushort* g0 = gb + goff + (size_t)(h * 128) * K + k0;
        load_lds_16B(g0,                   &sh[seg + (h * 128     ) * 64 + lds_u]);
        load_lds_16B(g0 + (size_t)64 * K,  &sh[seg + (h * 128 + 64) * 64 + lds_u]);
    };

    const int l15  = lane & 15;
    const int c16a = (((lane >> 4)    ) ^ (lane & 7)) * 8;
    const int c16b = (((lane >> 4) + 4) ^ (lane & 7)) * 8;
    const int arow = (wm * 128 + l15) * 64;
    const int brow = (wn * 64  + l15) * 64;

    f32x4 acc[8][4];
#pragma unroll
    for (int m = 0; m < 8; ++m)
#pragma unroll
        for (int n = 0; n < 4; ++n)
            acc[m][n] = (f32x4)(0.0f);

    short8v bfr[4][2];
    short8v af[2][2];

    // ---- prologue
    stage_half(A, a_off, SEG_A0, 0, 0);
    stage_half(A, a_off, SEG_A0, 1, 0);
    stage_half(W, w_off, SEG_B0, 0, 0);
    stage_half(W, w_off, SEG_B0, 1, 0);
    stage_half(W, w_off, SEG_B1, 0, 64);
    stage_half(W, w_off, SEG_B1, 1, 64);
    VMCNT4();
    BAR();

    // ---- main loop
    for (int i = 0; i < NI - 1; ++i) {
        const int kA1 = (2 * i + 1) * 64;
        const int kN2 = (2 * i + 2) * 64;
        const int kB3 = (2 * i + 3) * 64;

        READ_B_ALL(SEG_B0); READ_A2(SEG_A0, 0);
        stage_half(A, a_off, SEG_A1, 0, kA1);
        BAR(); MFMA16(0); BAR();

        READ_A2(SEG_A0, 2);
        stage_half(A, a_off, SEG_A1, 1, kA1);
        BAR(); MFMA16(2); BAR();

        READ_A2(SEG_A0, 4);
        stage_half(W, w_off, SEG_B0, 0, kN2);
        BAR(); MFMA16(4); BAR();

        READ_A2(SEG_A0, 6);
        stage_half(W, w_off, SEG_B0, 1, kN2);
        BAR(); MFMA16(6);
        VMCNT4();
        BAR();

        READ_B_ALL(SEG_B1); READ_A2(SEG_A1, 0);
        stage_half(A, a_off, SEG_A0, 0, kN2);
        BAR(); MFMA16(0); BAR();

        READ_A2(SEG_A1, 2);
        stage_half(A, a_off, SEG_A0, 1, kN2);
        BAR(); MFMA16(2); BAR();

        READ_A2(SEG_A1, 4);
        stage_half(W, w_off, SEG_B1, 0, kB3);
        BAR(); MFMA16(4); BAR();

        READ_A2(SEG_A1, 6);
        stage_half(W, w_off, SEG_B1, 1, kB3);
        BAR(); MFMA16(6);
        VMCNT4();
        BAR();
    }

    // ---- tail iter (tiles NT-2, NT-1)
    {
        const int kA1 = (NT - 1) * 64;
        READ_B_ALL(SEG_B0); READ_A2(SEG_A0, 0);
        stage_half(A, a_off, SEG_A1, 0, kA1);
        BAR(); MFMA16(0); BAR();
        READ_A2(SEG_A0, 2);
        stage_half(A, a_off, SEG_A1, 1, kA1);
        BAR(); MFMA16(2); BAR();
        READ_A2(SEG_A0, 4); BAR(); MFMA16(4); BAR();
        READ_A2(SEG_A0, 6); BAR(); MFMA16(6);
        VMCNT0();
        BAR();
        READ_B_ALL(SEG_B1); READ_A2(SEG_A1, 0); BAR(); MFMA16(0); BAR();
        READ_A2(SEG_A1, 2); BAR(); MFMA16(2); BAR();
        READ_A2(SEG_A1, 4); BAR(); MFMA16(4); BAR();
        READ_A2(SEG_A1, 6); BAR(); MFMA16(6);
    }

    // ---- epilogue: acc -> bf16 LDS tile [256][256] -> coalesced global stores
    float bb[4];
#pragma unroll
    for (int nf = 0; nf < 4; ++nf)
        bb[nf] = bias[col0 + wn * 64 + nf * 16 + l15];

    __syncthreads();   // all waves' ds_reads consumed (vmcnt already 0): sh reusable
#pragma unroll
    for (int mf = 0; mf < 8; ++mf) {
        const int rl = wm * 128 + mf * 16 + (lane >> 4) * 4;
#pragma unroll
        for (int nf = 0; nf < 4; ++nf) {
            const int cl = wn * 64 + nf * 16 + l15;
#pragma unroll
            for (int j = 0; j < 4; ++j)
                sh[(rl + j) * 256 + cl] = (ushort)f2bf(acc[mf][nf][j] + bb[nf]);
        }
    }
    __syncthreads();
#pragma unroll
    for (int pass = 0; pass < 16; ++pass) {
        const int r = pass * 16 + (tid >> 5);
        const int c = (tid & 31) * 8;
        *reinterpret_cast<short8v*>(&C[(size_t)(row0 + r) * V + col0 + c]) =
            *reinterpret_cast<const short8v*>(&sh[r * 256 + c]);
    }
}

// ---------------- fused row stats + loss (bf16 logits) ----------------
__global__ void zero_accum_kernel(double* accum) {
    accum[0] = 0.0; accum[1] = 0.0;
}

__global__ __launch_bounds__(1024)
void stats_loss_kernel(const ushort* __restrict__ S, const ushort* __restrict__ Tm,
                       const int* __restrict__ tgt, double* __restrict__ accum, int V)
{
    const int r = blockIdx.x;
    const ushort* s = S  + (size_t)r * V;
    const ushort* t = Tm + (size_t)r * V;
    const int tid = threadIdx.x;

    // pass 1: per-row online stats.
    // e = exp((x-m)/2): lh += e (T=2 sum), l1 += e*e (T=1 sum). One exp serves both.
    float ms = -1e30f, l1 = 0.f, lh = 0.f;
    float mt = -1e30f, lt = 0.f;
    for (int v = tid * 8; v < V; v += 8192) {
        short8v sv = *reinterpret_cast<const short8v*>(&s[v]);
        short8v tv = *reinterpret_cast<const short8v*>(&t[v]);
#pragma unroll
        for (int j = 0; j < 8; ++j) {
            float x = bf2f((ushort)sv[j]);
            if (x > ms) {
                float eh = __expf(0.5f * (ms - x));
                lh *= eh; l1 *= eh * eh; ms = x;
            }
            float e = __expf(0.5f * (x - ms));
            lh += e; l1 += e * e;
            float y = bf2f((ushort)tv[j]);
            if (y > mt) {
                lt *= __expf(0.5f * (mt - y));
                mt = y;
            }
            lt += __expf(0.5f * (y - mt));
        }
    }
#pragma unroll
    for (int off = 32; off > 0; off >>= 1) {
        float mso = __shfl_xor(ms, off), l1o = __shfl_xor(l1, off), lho = __shfl_xor(lh, off);
        float mn = fmaxf(ms, mso);
        float ea = __expf(0.5f * (ms - mn)), eb = __expf(0.5f * (mso - mn));
        lh = lh * ea + lho * eb;
        l1 = l1 * ea * ea + l1o * eb * eb;
        ms = mn;
        float mto = __shfl_xor(mt, off), lto = __shfl_xor(lt, off);
        float mn2 = fmaxf(mt, mto);
        lt = lt * __expf(0.5f * (mt - mn2)) + lto * __expf(0.5f * (mto - mn2));
        mt = mn2;
    }
    __shared__ float red[16][5];
    __shared__ float bc[3];
    if ((tid & 63) == 0) {
        int w = tid >> 6;
        red[w][0] = ms; red[w][1] = l1; red[w][2] = lh;
        red[w][3] = mt; red[w][4] = lt;
    }
    __syncthreads();
    if (tid == 0) {
        float M = red[0][0], L1 = red[0][1], LH = red[0][2];
        float Mt = red[0][3], Lt = red[0][4];
#pragma unroll
        for (int w = 1; w < 16; ++w) {
            float mn = fmaxf(M, red[w][0]);
            float ea = __expf(0.5f * (M - mn)), eb = __expf(0.5f * (red[w][0] - mn));
            LH = LH * ea + red[w][2] * eb;
            L1 = L1 * ea * ea + red[w][1] * eb * eb;
            M = mn;
            float mn2 = fmaxf(Mt, red[w][3]);
            Lt = Lt * __expf(0.5f * (Mt - mn2)) + red[w][4] * __expf(0.5f * (red[w][3] - mn2));
            Mt = mn2;
        }
        bc[0] = M + __logf(L1);             // lse_s (T=1)
        bc[1] = 0.5f * M + __logf(LH);      // lse_s (T=2)
        bc[2] = 0.5f * Mt + __logf(Lt);     // lse_t (T=2)
    }
    __syncthreads();
    const float ls1 = bc[0], ls2 = bc[1], lt2 = bc[2];

    // pass 2: JSD (rows L2/L3-resident after pass 1)
    float local = 0.f;
    for (int v = tid * 8; v < V; v += 8192) {
        short8v sv = *reinterpret_cast<const short8v*>(&s[v]);
        short8v tv = *reinterpret_cast<const short8v*>(&t[v]);
#pragma unroll
        for (int j = 0; j < 8; ++j) {
            float sp = 0.5f * bf2f((ushort)sv[j]) - ls2;
            float tp = 0.5f * bf2f((ushort)tv[j]) - lt2;
            float p = __expf(sp), q = __expf(tp);
            float mm = 0.5f * (p + q);
            float lm = __logf(fmaxf(mm, 1e-38f));
            local += 0.5f * (p * (sp - lm) + q * (tp - lm));
        }
    }
#pragma unroll
    for (int off = 32; off > 0; off >>= 1)
        local += __shfl_xor(local, off);
    __shared__ float ls[16];
    if ((tid & 63) == 0) ls[tid >> 6] = local;
    __syncthreads();
    if (tid == 0) {
        float blocksum = 0.f;
#pragma unroll
        for (int w = 0; w < 16; ++w) blocksum += ls[w];
        atomicAdd(&accum[1], (double)blocksum);
        int tg = tgt[r];
        if (tg != -100) {
            float nll = -(bf2f(s[tg]) - ls1);
            atomicAdd(&accum[0], (double)nll);
        }
    }
}

__global__ void finalize_kernel(const double* __restrict__ accum,
                                float* __restrict__ out, double inv_n) {
    out[0] = (float)(0.5 * (accum[0] * inv_n) + 0.5 * (accum[1] * inv_n));
}

extern "C" void kernel_launch(void* const* d_in, const int* in_sizes, int n_in,
                              void* d_out, int out_size, void* d_ws, size_t ws_size,
                              hipStream_t stream)
{
    const float* s_in = (const float*)d_in[0];   // [N, 2048]
    const float* s_w  = (const float*)d_in[1];   // [V, 2048]
    const float* s_b  = (const float*)d_in[2];   // [V]
    const float* t_in = (const float*)d_in[3];   // [N, 4096]
    const float* t_w  = (const float*)d_in[4];   // [V, 4096]
    const float* t_b  = (const float*)d_in[5];   // [V]
    const int*   tgt  = (const int*)d_in[6];     // [N]

    const int N = 2048, V = 32000, KS = 2048, KT = 4096;

    const size_t e_sin = (size_t)N * KS;
    const size_t e_sw  = (size_t)V * KS;
    const size_t e_tin = (size_t)N * KT;
    const size_t e_tw  = (size_t)V * KT;
    const size_t bf16_bytes = 2 * (e_sin + e_sw + e_tin + e_tw);   // 418,381,824

    char* ws = (char*)d_ws;
    double* accum = (double*)ws;

    ushort* s_in_b = (ushort*)(ws + 4096);
    ushort* s_w_b  = s_in_b + e_sin;
    ushort* t_in_b = s_w_b + e_sw;
    ushort* t_w_b  = t_in_b + e_tin;
    ushort* s_log  = (ushort*)(ws + 4096 + bf16_bytes);
    ushort* t_log  = s_log + (size_t)N * V;

    zero_accum_kernel<<<1, 1, 0, stream>>>(accum);

    // fused convert: dst regions are contiguous starting at s_in_b
    const size_t c0 = e_sin / 8;
    const size_t c1 = c0 + e_sw / 8;
    const size_t c2 = c1 + e_tin / 8;
    const size_t c3 = c2 + e_tw / 8;
    cvt4_kernel<<<2048, 256, 0, stream>>>(s_in, s_w, t_in, t_w, s_in_b, c0, c1, c2, c3);

    const int grid = (V / 256) * (N / 256);   // 125 * 8 = 1000, %8==0
    gemm256_kernel<<<grid, 512, 0, stream>>>(s_in_b, s_w_b, s_b, s_log, KS, V);
    gemm256_kernel<<<grid, 512, 0, stream>>>(t_in_b, t_w_b, t_b, t_log, KT, V);

    stats_loss_kernel<<<N, 1024, 0, stream>>>(s_log, t_log, tgt, accum, V);

    finalize_kernel<<<1, 1, 0, stream>>>(accum, (float*)d_out, 1.0 / (double)N);
}